// Round 21
// baseline (1003.691 us; speedup 1.0000x reference)
//
#include <hip/hip_runtime.h>

typedef _Float16 half8 __attribute__((ext_vector_type(8)));
typedef _Float16 half4v __attribute__((ext_vector_type(4)));
typedef float floatx16 __attribute__((ext_vector_type(16)));
typedef float float4v __attribute__((ext_vector_type(4)));

#define MTOT 131072   // B*T rows
#define DDIM 1024
#define TLEN 4096
#define BATCH 32
#define NMASK 2048

// --------- kernel 0: pack W1 into MFMA B-fragment order, fp16-split (x512) ----
__global__ void k_wpack(const float* __restrict__ W1, _Float16* __restrict__ Wp)
{
  const int f = blockIdx.x * 4 + (threadIdx.x >> 6);  // 0..2047
  const int l = threadIdx.x & 63;
  const int cb = f >> 6, kb = f & 63;
  const int col = cb * 32 + (l & 31);
  const int k0 = kb * 16 + (l >> 5) * 8;
  half8 hv, lv;
#pragma unroll
  for (int j = 0; j < 8; j++) {
    float w = W1[(size_t)(k0 + j) * DDIM + col] * 512.0f;
    _Float16 h = (_Float16)w;
    hv[j] = h; lv[j] = (_Float16)(w - (float)h);
  }
  *(half8*)(Wp + ((size_t)(f * 2 + 0) * 64 + l) * 8) = hv;
  *(half8*)(Wp + ((size_t)(f * 2 + 1) * 64 + l) * 8) = lv;
}

// --------- kernel 1: fused scores GEMM ----------------------------------------
// BK=128 SINGLE-BUFFER variant: tile 64 rows x 256 cols, 4 waves x 64x64 cols,
// (256,3) = 3 staggered blocks/CU. Per t (8 total): 8 kc-steps (96 MFMA/wave)
// between sync events — HALVES barriers/SPLITW-drains/LOADX per MFMA vs BK=64.
// LDS 32KB single buf (x3 blocks = 96KB). Layout: row stride 256 f16, two
// 16-chunk k-halves, each the verified XOR layout. R18/20's 0-conflict staging
// map (rr=tid>>4, cc=tid&15). B streamed per-kc from L2 (latency proven
// hidden). Raw s_barrier pair: [reads done] -> SPLITW -> [lgkm0, writes done].
__global__ __launch_bounds__(256, 3) void k_score(
    const float* __restrict__ x, const _Float16* __restrict__ Wp,
    const float* __restrict__ b1, const float* __restrict__ w2,
    float* __restrict__ partials)
{
  __shared__ __align__(16) _Float16 Abuf[64 * 256];   // 32 KB, single buffer
  __shared__ float part_lds[4][64];

  const int tid  = threadIdx.x;
  const int lane = tid & 63;
  const int wn   = tid >> 6;               // wave = 64-col group 0..3
  const int l31 = lane & 31, l5 = lane >> 5;

  // XCD-bijective decode: 4 col-blocks of a row-panel land on one XCD.
  const int id  = blockIdx.x;              // 8192 blocks
  const int xcd = id & 7, seq = id >> 3;
  const int px  = seq & 3;                 // col-block 0..3
  const int py  = (seq >> 2) * 8 + xcd;    // row-panel 0..2047 (64 rows each)
  const int m0 = py * 64;

  // A staging: thread -> rows {rr,+16,+32,+48} x k-halves {0,1}, f32-quad cc
  const int rr = tid >> 4;                 // 0..15
  const int cc = tid & 15;                 // quad 0..15
  const float* xs = x + (size_t)(m0 + rr) * DDIM + cc * 4;

  // B fragment bases: col-groups cb = px*8 + wn*2 + nf; frag (cb*64 + t*8 + kc)
  const _Float16* wpb0 = Wp + (size_t)(px * 8 + wn * 2 + 0) * 64 * 1024 + lane * 8;
  const _Float16* wpb1 = Wp + (size_t)(px * 8 + wn * 2 + 1) * 64 * 1024 + lane * 8;

  // ---- precomputed LDS offsets (t-invariant; row stride 256 f16) ----
  // kc 0..7: within-half kcm = kc&3; k-half offset +128 f16 folded as
  // compile-time immediate in unrolled KCSTEP.
  int roff[2][4][2];
#pragma unroll
  for (int mf = 0; mf < 2; mf++) {
    int r = mf * 32 + l31;
#pragma unroll
    for (int kcm = 0; kcm < 4; kcm++) {
      roff[mf][kcm][0] = r * 256 + (((    kcm * 2 + l5)) ^ (r & 15)) * 8;
      roff[mf][kcm][1] = r * 256 + (((8 + kcm * 2 + l5)) ^ (r & 15)) * 8;
    }
  }
  int woffH[4], woffL[4];                  // per row-group k; +h*128 for k-half
  {
    int Phi = (cc >> 1) ^ rr;              // rr < 16; proven-0-conflict pattern
    int so = (cc & 1) * 4;
#pragma unroll
    for (int k = 0; k < 4; k++) {
      woffH[k] = (rr + 16 * k) * 256 + Phi * 8 + so;
      woffL[k] = (rr + 16 * k) * 256 + (Phi ^ 8) * 8 + so;
    }
  }

  floatx16 acc[2][2] = {};                 // [mf][nf]
  float4v xv[8];                           // 32 f32/thread, static-indexed

#define LOADX(T)                                                        \
  _Pragma("unroll")                                                     \
  for (int k = 0; k < 4; k++)                                           \
    _Pragma("unroll")                                                   \
    for (int h = 0; h < 2; h++)                                         \
      xv[k * 2 + h] = *(const float4v*)(xs + (size_t)k * 16 * DDIM + (T) * 128 + h * 64);

#define SPLITW()                                                        \
  _Pragma("unroll")                                                     \
  for (int k = 0; k < 4; k++)                                           \
    _Pragma("unroll")                                                   \
    for (int h = 0; h < 2; h++) {                                       \
      half4v hv, lv;                                                    \
      _Pragma("unroll")                                                 \
      for (int j = 0; j < 4; j++) {                                     \
        _Float16 hh = (_Float16)xv[k * 2 + h][j];                       \
        hv[j] = hh; lv[j] = (_Float16)(xv[k * 2 + h][j] - (float)hh);   \
      }                                                                 \
      *(half4v*)&Abuf[woffH[k] + h * 128] = hv;                         \
      *(half4v*)&Abuf[woffL[k] + h * 128] = lv;                         \
    }

  // one kc-slice (kc = compile-time 0..7): 4 ds_read_b128 + 4 B-loads + 12 MFMA
#define KCSTEP(TQ, KC)                                                  \
  {                                                                     \
    const int hof = ((KC) >= 4) ? 128 : 0;                              \
    half8 bh0 = *(const half8*)(wpb0 + (size_t)((TQ) + (KC)) * 1024);   \
    half8 bl0 = *(const half8*)(wpb0 + (size_t)((TQ) + (KC)) * 1024 + 512); \
    half8 bh1 = *(const half8*)(wpb1 + (size_t)((TQ) + (KC)) * 1024);   \
    half8 bl1 = *(const half8*)(wpb1 + (size_t)((TQ) + (KC)) * 1024 + 512); \
    _Pragma("unroll")                                                   \
    for (int mf = 0; mf < 2; mf++) {                                    \
      half8 ah = *(const half8*)&Abuf[roff[mf][(KC) & 3][0] + hof];     \
      half8 al = *(const half8*)&Abuf[roff[mf][(KC) & 3][1] + hof];     \
      acc[mf][0] = __builtin_amdgcn_mfma_f32_32x32x16_f16(ah, bh0, acc[mf][0], 0, 0, 0); \
      acc[mf][0] = __builtin_amdgcn_mfma_f32_32x32x16_f16(ah, bl0, acc[mf][0], 0, 0, 0); \
      acc[mf][0] = __builtin_amdgcn_mfma_f32_32x32x16_f16(al, bh0, acc[mf][0], 0, 0, 0); \
      acc[mf][1] = __builtin_amdgcn_mfma_f32_32x32x16_f16(ah, bh1, acc[mf][1], 0, 0, 0); \
      acc[mf][1] = __builtin_amdgcn_mfma_f32_32x32x16_f16(ah, bl1, acc[mf][1], 0, 0, 0); \
      acc[mf][1] = __builtin_amdgcn_mfma_f32_32x32x16_f16(al, bh1, acc[mf][1], 0, 0, 0); \
    }                                                                   \
  }

  // ---- prologue: K-tile 0 -> buf ----
  LOADX(0)
  SPLITW()
  __syncthreads();

#pragma unroll 1
  for (int t = 0; t < 8; ++t) {
    const int tq = t * 8;
    __builtin_amdgcn_s_setprio(1);
    KCSTEP(tq, 0)
    KCSTEP(tq, 1)
    KCSTEP(tq, 2)
    KCSTEP(tq, 3)
    __builtin_amdgcn_s_setprio(0);
    if (t < 7) LOADX(t + 1)                // youngest VMEM; consumed by SPLITW
    __builtin_amdgcn_s_setprio(1);
    KCSTEP(tq, 4)
    KCSTEP(tq, 5)
    KCSTEP(tq, 6)
    KCSTEP(tq, 7)
    __builtin_amdgcn_s_setprio(0);
    // barrier 1: all waves done READING buf this t
    __builtin_amdgcn_sched_barrier(0);
    __builtin_amdgcn_s_barrier();
    if (t < 7) SPLITW()                    // overwrite buf with tile t+1
    // barrier 2: writes visible
    asm volatile("s_waitcnt lgkmcnt(0)" ::: "memory");
    __builtin_amdgcn_sched_barrier(0);
    __builtin_amdgcn_s_barrier();
  }
#undef LOADX
#undef SPLITW
#undef KCSTEP

  // ---- epilogue: tanh + dot(w2) + row reduce (64 cols per wave, 2 nf) ----
  float b1v[2], w2v[2];
#pragma unroll
  for (int nf = 0; nf < 2; nf++) {
    int col = px * 256 + wn * 64 + nf * 32 + l31;
    b1v[nf] = b1[col];
    w2v[nf] = w2[col];
  }
  const float inv512 = 1.0f / 512.0f;
#pragma unroll
  for (int mf = 0; mf < 2; mf++)
#pragma unroll
    for (int reg = 0; reg < 16; reg++) {
      float s = 0.0f;
#pragma unroll
      for (int nf = 0; nf < 2; nf++) {
        float pre = acc[mf][nf][reg] * inv512 + b1v[nf];
        float a = fabsf(pre);
        float e = __expf(-2.0f * a);
        float tt = (1.0f - e) / (1.0f + e);           // tanh(|pre|)
        s += copysignf(tt, pre) * w2v[nf];
      }
#pragma unroll
      for (int off = 1; off < 32; off <<= 1) s += __shfl_xor(s, off, 64);
      if (l31 == 0)
        part_lds[wn][mf * 32 + (reg & 3) + 8 * (reg >> 2) + 4 * l5] = s;
    }
  __syncthreads();
  if (tid < 64) {
    float v = part_lds[0][tid] + part_lds[1][tid] + part_lds[2][tid] + part_lds[3][tid];
    partials[(size_t)px * MTOT + m0 + tid] = v;
  }
}

// --------- kernel 2: per-batch-row exact select (stable-argsort semantics) + softmax
__global__ void k_select(const float* __restrict__ partials, const float* __restrict__ b2,
                         float* __restrict__ weights)
{
  __shared__ float s_lds[TLEN];
  __shared__ unsigned long long keys[TLEN];
  __shared__ float red[20];
  const int b = blockIdx.x, tid = threadIdx.x;
  const float b2v = b2[0];

  for (int i = tid; i < TLEN; i += 1024) {
    size_t idx = (size_t)b * TLEN + i;
    float s = partials[idx] + partials[idx + (size_t)MTOT] +
              partials[idx + 2 * (size_t)MTOT] + partials[idx + 3 * (size_t)MTOT] + b2v;
    s_lds[i] = s;
    unsigned u = __float_as_uint(s);
    u = (u & 0x80000000u) ? ~u : (u | 0x80000000u);  // order-preserving float->uint
    keys[i] = ((unsigned long long)u << 32) | (unsigned)i;
  }
  __syncthreads();
  // bitonic sort ascending (key = (score, index) — matches stable argsort)
  for (int k = 2; k <= TLEN; k <<= 1)
    for (int j = k >> 1; j > 0; j >>= 1) {
      for (int i = tid; i < TLEN; i += 1024) {
        int p = i ^ j;
        if (p > i) {
          unsigned long long a = keys[i], c = keys[p];
          bool up = ((i & k) == 0);
          if ((a > c) == up) { keys[i] = c; keys[p] = a; }
        }
      }
      __syncthreads();
    }

  const unsigned long long thr = keys[NMASK];        // first KEPT pair
  unsigned um = (unsigned)(keys[TLEN - 1] >> 32);    // decode row max
  um = (um & 0x80000000u) ? (um ^ 0x80000000u) : ~um;
  const float m = __uint_as_float(um);

  float ev[4]; bool kp[4]; float zp = 0.0f;
#pragma unroll
  for (int q = 0; q < 4; q++) {
    int i = tid + q * 1024;
    float s = s_lds[i];
    unsigned u = __float_as_uint(s);
    u = (u & 0x80000000u) ? ~u : (u | 0x80000000u);
    unsigned long long key = ((unsigned long long)u << 32) | (unsigned)i;
    kp[q] = (key >= thr);
    ev[q] = __expf(s - m);
    if (kp[q]) zp += ev[q];
  }
#pragma unroll
  for (int off = 1; off < 64; off <<= 1) zp += __shfl_xor(zp, off, 64);
  if ((tid & 63) == 0) red[tid >> 6] = zp;
  __syncthreads();
  if (tid == 0) { float z = 0.0f; for (int i = 0; i < 16; i++) z += red[i]; red[16] = z; }
  __syncthreads();
  const float invZ = 1.0f / red[16];
#pragma unroll
  for (int q = 0; q < 4; q++) {
    int i = tid + q * 1024;
    weights[(size_t)b * TLEN + i] = kp[q] ? ev[q] * invZ : 0.0f;
  }
}

// --------- kernel 3: masked_output = x * weights[row]; skip x-read when w==0 --
__global__ void k_scale(const float* __restrict__ x, const float* __restrict__ weights,
                        float* __restrict__ out)
{
  const size_t n4 = (size_t)MTOT * DDIM / 4;
  for (size_t f = (size_t)blockIdx.x * blockDim.x + threadIdx.x; f < n4;
       f += (size_t)gridDim.x * blockDim.x) {
    float w = weights[f >> 8];                       // 256 float4 per row
    float4v o;
    if (w != 0.0f) {                                 // wave-uniform (row-granular)
      float4v v = ((const float4v*)x)[f];
      o = v * w;
    } else {
      o = (float4v){0.0f, 0.0f, 0.0f, 0.0f};         // x*0 == ±0; |Δ| = 0
    }
    ((float4v*)out)[f] = o;
  }
}

extern "C" void kernel_launch(void* const* d_in, const int* in_sizes, int n_in,
                              void* d_out, int out_size, void* d_ws, size_t ws_size,
                              hipStream_t stream)
{
  const float* x  = (const float*)d_in[0];
  const float* W1 = (const float*)d_in[1];
  const float* b1 = (const float*)d_in[2];
  const float* w2 = (const float*)d_in[3];
  const float* b2 = (const float*)d_in[4];
  float* out = (float*)d_out;
  float* weights = out + (size_t)MTOT * DDIM;        // output 1 region

  char* ws = (char*)d_ws;                            // 6 MiB total
  _Float16* Wp    = (_Float16*)ws;                   // 4 MiB
  float*    parts = (float*)(ws + (4u << 20));       // 2 MiB

  k_wpack<<<512, 256, 0, stream>>>(W1, Wp);          // 2048 frags x 4/block
  k_score<<<8192, 256, 0, stream>>>(x, Wp, b1, w2, parts);
  k_select<<<BATCH, 1024, 0, stream>>>(parts, b2, weights);
  k_scale<<<2048, 256, 0, stream>>>(x, weights, out);
}

// Round 22
// 978.097 us; speedup vs baseline: 1.0262x; 1.0262x over previous
//
#include <hip/hip_runtime.h>

typedef _Float16 half8 __attribute__((ext_vector_type(8)));
typedef _Float16 half4v __attribute__((ext_vector_type(4)));
typedef float floatx16 __attribute__((ext_vector_type(16)));
typedef float float4v __attribute__((ext_vector_type(4)));

#define MTOT 131072   // B*T rows
#define DDIM 1024
#define TLEN 4096
#define BATCH 32
#define NMASK 2048

// --------- kernel 0: pack W1 into MFMA B-fragment order, fp16-split (x512) ----
__global__ void k_wpack(const float* __restrict__ W1, _Float16* __restrict__ Wp)
{
  const int f = blockIdx.x * 4 + (threadIdx.x >> 6);  // 0..2047
  const int l = threadIdx.x & 63;
  const int cb = f >> 6, kb = f & 63;
  const int col = cb * 32 + (l & 31);
  const int k0 = kb * 16 + (l >> 5) * 8;
  half8 hv, lv;
#pragma unroll
  for (int j = 0; j < 8; j++) {
    float w = W1[(size_t)(k0 + j) * DDIM + col] * 512.0f;
    _Float16 h = (_Float16)w;
    hv[j] = h; lv[j] = (_Float16)(w - (float)h);
  }
  *(half8*)(Wp + ((size_t)(f * 2 + 0) * 64 + l) * 8) = hv;
  *(half8*)(Wp + ((size_t)(f * 2 + 1) * 64 + l) * 8) = lv;
}

// --------- kernel 1: fused scores GEMM (best measured config: R19, 978us) ----
// tile 64 rows x 256 cols, 4 waves x 64x64 cols (12 MFMA per A-frag ds_read),
// (256,3) = 3 staggered blocks/CU. B streamed per-kc from L2; xv issued last
// (youngest in in-order vmcnt queue); raw s_barrier + lgkmcnt(0).
// Family ceiling established R9-R21: ~53% MfmaUtil across 4 structures.
__global__ __launch_bounds__(256, 3) void k_score(
    const float* __restrict__ x, const _Float16* __restrict__ Wp,
    const float* __restrict__ b1, const float* __restrict__ w2,
    float* __restrict__ partials)
{
  __shared__ __align__(16) _Float16 Abuf[2][64 * 128];   // 16 KB each
  __shared__ float part_lds[4][64];

  const int tid  = threadIdx.x;
  const int lane = tid & 63;
  const int wn   = tid >> 6;               // wave = 64-col group 0..3
  const int l31 = lane & 31, l5 = lane >> 5;

  // XCD-bijective decode: 4 col-blocks of a row-panel land on one XCD.
  const int id  = blockIdx.x;              // 8192 blocks
  const int xcd = id & 7, seq = id >> 3;
  const int px  = seq & 3;                 // col-block 0..3
  const int py  = (seq >> 2) * 8 + xcd;    // row-panel 0..2047 (64 rows each)
  const int m0 = py * 64;

  // A staging: thread -> row rr (0..63), f32-quads {cq, cq+4, cq+8, cq+12}
  const int rr = tid >> 2;                 // 0..63
  const int cq = tid & 3;                  // base quad
  const float* xs = x + (size_t)(m0 + rr) * DDIM + cq * 4;

  // B fragment bases: col-groups cb = px*8 + wn*2 + nf
  const _Float16* wpb0 = Wp + (size_t)(px * 8 + wn * 2 + 0) * 64 * 1024 + lane * 8;
  const _Float16* wpb1 = Wp + (size_t)(px * 8 + wn * 2 + 1) * 64 * 1024 + lane * 8;

  // ---- precomputed LDS offsets (t-invariant; verified XOR layout) ----
  int roff[2][4][2];
#pragma unroll
  for (int mf = 0; mf < 2; mf++) {
    int r = mf * 32 + l31;
#pragma unroll
    for (int kc = 0; kc < 4; kc++) {
      roff[mf][kc][0] = r * 128 + (((    kc * 2 + l5)) ^ (r & 15)) * 8;
      roff[mf][kc][1] = r * 128 + (((8 + kc * 2 + l5)) ^ (r & 15)) * 8;
    }
  }
  int woffH[4], woffL[4];
#pragma unroll
  for (int i = 0; i < 4; i++) {
    int q = cq + 4 * i;
    int Phi = (q >> 1) ^ (rr & 15);
    int so = (q & 1) * 4;
    woffH[i] = rr * 128 + Phi * 8 + so;
    woffL[i] = rr * 128 + (Phi ^ 8) * 8 + so;
  }

  floatx16 acc[2][2] = {};                 // [mf][nf]
  float4v xv[4];                           // 16 elems/thread, static-indexed

#define LOADX(T)                                                        \
  _Pragma("unroll")                                                     \
  for (int i = 0; i < 4; i++)                                           \
    xv[i] = *(const float4v*)(xs + (T) * 64 + i * 16);

#define SPLITW(DST)                                                     \
  _Pragma("unroll")                                                     \
  for (int i = 0; i < 4; i++) {                                         \
    half4v hv, lv;                                                      \
    _Pragma("unroll")                                                   \
    for (int j = 0; j < 4; j++) {                                       \
      _Float16 h = (_Float16)xv[i][j];                                  \
      hv[j] = h; lv[j] = (_Float16)(xv[i][j] - (float)h);               \
    }                                                                   \
    *(half4v*)&(DST)[woffH[i]] = hv;                                    \
    *(half4v*)&(DST)[woffL[i]] = lv;                                    \
  }

  // one kc-slice: 4 ds_read_b128 + 8 B-loads(L2) + 12 MFMA
#define KCSTEP(AB, TQ, KC)                                              \
  {                                                                     \
    half8 bh0 = *(const half8*)(wpb0 + (size_t)((TQ) + (KC)) * 1024);   \
    half8 bl0 = *(const half8*)(wpb0 + (size_t)((TQ) + (KC)) * 1024 + 512); \
    half8 bh1 = *(const half8*)(wpb1 + (size_t)((TQ) + (KC)) * 1024);   \
    half8 bl1 = *(const half8*)(wpb1 + (size_t)((TQ) + (KC)) * 1024 + 512); \
    _Pragma("unroll")                                                   \
    for (int mf = 0; mf < 2; mf++) {                                    \
      half8 ah = *(const half8*)&(AB)[roff[mf][KC][0]];                 \
      half8 al = *(const half8*)&(AB)[roff[mf][KC][1]];                 \
      acc[mf][0] = __builtin_amdgcn_mfma_f32_32x32x16_f16(ah, bh0, acc[mf][0], 0, 0, 0); \
      acc[mf][0] = __builtin_amdgcn_mfma_f32_32x32x16_f16(ah, bl0, acc[mf][0], 0, 0, 0); \
      acc[mf][0] = __builtin_amdgcn_mfma_f32_32x32x16_f16(al, bh0, acc[mf][0], 0, 0, 0); \
      acc[mf][1] = __builtin_amdgcn_mfma_f32_32x32x16_f16(ah, bh1, acc[mf][1], 0, 0, 0); \
      acc[mf][1] = __builtin_amdgcn_mfma_f32_32x32x16_f16(ah, bl1, acc[mf][1], 0, 0, 0); \
      acc[mf][1] = __builtin_amdgcn_mfma_f32_32x32x16_f16(al, bh1, acc[mf][1], 0, 0, 0); \
    }                                                                   \
  }

  // ---- prologue: tile 0 -> buf 0 ----
  LOADX(0)
  SPLITW(Abuf[0])
  __syncthreads();

#pragma unroll 1
  for (int t = 0; t < 16; ++t) {
    const _Float16* ab = Abuf[t & 1];
    _Float16* abn = Abuf[(t & 1) ^ 1];
    const int tq = t * 4;
    __builtin_amdgcn_s_setprio(1);
    KCSTEP(ab, tq, 0)
    KCSTEP(ab, tq, 1)
    KCSTEP(ab, tq, 2)
    KCSTEP(ab, tq, 3)
    __builtin_amdgcn_s_setprio(0);
    if (t < 15) {
      LOADX(t + 1)                         // youngest VMEM: only SPLITW waits on it
      SPLITW(abn)                          // exposed wait absorbed by 3-way stagger
    }
    asm volatile("s_waitcnt lgkmcnt(0)" ::: "memory");
    __builtin_amdgcn_sched_barrier(0);
    __builtin_amdgcn_s_barrier();
  }
#undef LOADX
#undef SPLITW
#undef KCSTEP

  // ---- epilogue: tanh + dot(w2) + row reduce (64 cols per wave, 2 nf) ----
  float b1v[2], w2v[2];
#pragma unroll
  for (int nf = 0; nf < 2; nf++) {
    int col = px * 256 + wn * 64 + nf * 32 + l31;
    b1v[nf] = b1[col];
    w2v[nf] = w2[col];
  }
  const float inv512 = 1.0f / 512.0f;
#pragma unroll
  for (int mf = 0; mf < 2; mf++)
#pragma unroll
    for (int reg = 0; reg < 16; reg++) {
      float s = 0.0f;
#pragma unroll
      for (int nf = 0; nf < 2; nf++) {
        float pre = acc[mf][nf][reg] * inv512 + b1v[nf];
        float a = fabsf(pre);
        float e = __expf(-2.0f * a);
        float tt = (1.0f - e) / (1.0f + e);           // tanh(|pre|)
        s += copysignf(tt, pre) * w2v[nf];
      }
#pragma unroll
      for (int off = 1; off < 32; off <<= 1) s += __shfl_xor(s, off, 64);
      if (l31 == 0)
        part_lds[wn][mf * 32 + (reg & 3) + 8 * (reg >> 2) + 4 * l5] = s;
    }
  __syncthreads();
  if (tid < 64) {
    float v = part_lds[0][tid] + part_lds[1][tid] + part_lds[2][tid] + part_lds[3][tid];
    partials[(size_t)px * MTOT + m0 + tid] = v;
  }
}

// --------- kernel 2: per-batch-row exact select (stable-argsort semantics) + softmax
__global__ void k_select(const float* __restrict__ partials, const float* __restrict__ b2,
                         float* __restrict__ weights)
{
  __shared__ float s_lds[TLEN];
  __shared__ unsigned long long keys[TLEN];
  __shared__ float red[20];
  const int b = blockIdx.x, tid = threadIdx.x;
  const float b2v = b2[0];

  for (int i = tid; i < TLEN; i += 1024) {
    size_t idx = (size_t)b * TLEN + i;
    float s = partials[idx] + partials[idx + (size_t)MTOT] +
              partials[idx + 2 * (size_t)MTOT] + partials[idx + 3 * (size_t)MTOT] + b2v;
    s_lds[i] = s;
    unsigned u = __float_as_uint(s);
    u = (u & 0x80000000u) ? ~u : (u | 0x80000000u);  // order-preserving float->uint
    keys[i] = ((unsigned long long)u << 32) | (unsigned)i;
  }
  __syncthreads();
  // bitonic sort ascending (key = (score, index) — matches stable argsort)
  for (int k = 2; k <= TLEN; k <<= 1)
    for (int j = k >> 1; j > 0; j >>= 1) {
      for (int i = tid; i < TLEN; i += 1024) {
        int p = i ^ j;
        if (p > i) {
          unsigned long long a = keys[i], c = keys[p];
          bool up = ((i & k) == 0);
          if ((a > c) == up) { keys[i] = c; keys[p] = a; }
        }
      }
      __syncthreads();
    }

  const unsigned long long thr = keys[NMASK];        // first KEPT pair
  unsigned um = (unsigned)(keys[TLEN - 1] >> 32);    // decode row max
  um = (um & 0x80000000u) ? (um ^ 0x80000000u) : ~um;
  const float m = __uint_as_float(um);

  float ev[4]; bool kp[4]; float zp = 0.0f;
#pragma unroll
  for (int q = 0; q < 4; q++) {
    int i = tid + q * 1024;
    float s = s_lds[i];
    unsigned u = __float_as_uint(s);
    u = (u & 0x80000000u) ? ~u : (u | 0x80000000u);
    unsigned long long key = ((unsigned long long)u << 32) | (unsigned)i;
    kp[q] = (key >= thr);
    ev[q] = __expf(s - m);
    if (kp[q]) zp += ev[q];
  }
#pragma unroll
  for (int off = 1; off < 64; off <<= 1) zp += __shfl_xor(zp, off, 64);
  if ((tid & 63) == 0) red[tid >> 6] = zp;
  __syncthreads();
  if (tid == 0) { float z = 0.0f; for (int i = 0; i < 16; i++) z += red[i]; red[16] = z; }
  __syncthreads();
  const float invZ = 1.0f / red[16];
#pragma unroll
  for (int q = 0; q < 4; q++) {
    int i = tid + q * 1024;
    weights[(size_t)b * TLEN + i] = kp[q] ? ev[q] * invZ : 0.0f;
  }
}

// --------- kernel 3: masked_output = x * weights[row]; skip x-read when w==0 --
__global__ void k_scale(const float* __restrict__ x, const float* __restrict__ weights,
                        float* __restrict__ out)
{
  const size_t n4 = (size_t)MTOT * DDIM / 4;
  for (size_t f = (size_t)blockIdx.x * blockDim.x + threadIdx.x; f < n4;
       f += (size_t)gridDim.x * blockDim.x) {
    float w = weights[f >> 8];                       // 256 float4 per row
    float4v o;
    if (w != 0.0f) {                                 // wave-uniform (row-granular)
      float4v v = ((const float4v*)x)[f];
      o = v * w;
    } else {
      o = (float4v){0.0f, 0.0f, 0.0f, 0.0f};         // x*0 == ±0; |Δ| = 0
    }
    ((float4v*)out)[f] = o;
  }
}

extern "C" void kernel_launch(void* const* d_in, const int* in_sizes, int n_in,
                              void* d_out, int out_size, void* d_ws, size_t ws_size,
                              hipStream_t stream)
{
  const float* x  = (const float*)d_in[0];
  const float* W1 = (const float*)d_in[1];
  const float* b1 = (const float*)d_in[2];
  const float* w2 = (const float*)d_in[3];
  const float* b2 = (const float*)d_in[4];
  float* out = (float*)d_out;
  float* weights = out + (size_t)MTOT * DDIM;        // output 1 region

  char* ws = (char*)d_ws;                            // 6 MiB total
  _Float16* Wp    = (_Float16*)ws;                   // 4 MiB
  float*    parts = (float*)(ws + (4u << 20));       // 2 MiB

  k_wpack<<<512, 256, 0, stream>>>(W1, Wp);          // 2048 frags x 4/block
  k_score<<<8192, 256, 0, stream>>>(x, Wp, b1, w2, parts);
  k_select<<<BATCH, 1024, 0, stream>>>(parts, b2, weights);
  k_scale<<<2048, 256, 0, stream>>>(x, weights, out);
}